// Round 5
// baseline (329.818 us; speedup 1.0000x reference)
//
#include <hip/hip_runtime.h>

typedef __bf16 bf16;
typedef __bf16 bf16x8 __attribute__((ext_vector_type(8)));
typedef __bf16 bf16x4 __attribute__((ext_vector_type(4)));
typedef short  short4_ __attribute__((ext_vector_type(4)));
typedef float  f32x4  __attribute__((ext_vector_type(4)));

#define MFMA16(a, b, c)  __builtin_amdgcn_mfma_f32_16x16x32_bf16((a), (b), (c), 0, 0, 0)
#define MFMA161(a, b, c) __builtin_amdgcn_mfma_f32_16x16x16bf16_1k((a), (b), (c), 0, 0, 0)

// B=1, S=128, R=256, C=256, H=8, Ca=32.  M = S*R = 32768.
// OGh layout: [h][m][32]  (full-line writes per (s,h) block)

// ================= prep: weights transpose + bias repack =================
// biasC[h][tq][kt][quad][lc][rr]  <->  bias[q = tq*16+lc][k = kt*16+quad*4+rr][h]
__global__ __launch_bounds__(256) void prep_kernel(
    const float* __restrict__ bias,
    const float* __restrict__ w_q, const float* __restrict__ w_k,
    const float* __restrict__ w_v, const float* __restrict__ w_g,
    const float* __restrict__ w_o,
    float* __restrict__ biasC,
    bf16* __restrict__ Wqg, bf16* __restrict__ Wkv, bf16* __restrict__ Wo)
{
    const float norm = 0.17677669529663687f;  // 1/sqrt(32) baked into Wq
    const int gid = blockIdx.x * 256 + threadIdx.x;
    const int gsz = gridDim.x * 256;
    for (int u = gid; u < 851968; u += gsz) {
        if (u < 131072) {                 // Wqg[n][k]
            int n = u >> 8, k = u & 255;
            float v = (n < 256) ? w_q[k * 256 + n] * norm : w_g[k * 256 + (n - 256)];
            Wqg[u] = (bf16)v;
        } else if (u < 262144) {          // Wkv[n][k]
            int i = u - 131072;
            int n = i >> 8, k = i & 255;
            float v = (n < 256) ? w_k[k * 256 + n] : w_v[k * 256 + (n - 256)];
            Wkv[i] = (bf16)v;
        } else if (u < 327680) {          // Wo[c][hd]
            int i = u - 262144;
            int n = i >> 8, k = i & 255;
            Wo[i] = (bf16)w_o[k * 256 + n];
        } else {                          // biasC (transposed pack for S^T scores)
            int o = u - 327680;
            int rr = o & 3, lc = (o >> 2) & 15, quad = (o >> 6) & 3;
            int kt = (o >> 8) & 15, tq = (o >> 12) & 15, h = o >> 16;
            int q = tq * 16 + lc, k = kt * 16 + quad * 4 + rr;
            biasC[o] = bias[((q << 8) + k) * 8 + h];
        }
    }
}

// ========== proj: [QG|KV] = [q|kv](fp32) @ W^T.  512 thr, full-K + full-N ======
// Block: 128m x 512n; wave 64m x 128n (wr=wave&1, wc=wave>>1). One barrier total.
__global__ __launch_bounds__(512, 2) void proj_kernel(
    const float* __restrict__ qin, const float* __restrict__ kvin,
    const bf16* __restrict__ Wqg, const bf16* __restrict__ Wkv,
    bf16* __restrict__ QG, bf16* __restrict__ KV)
{
    __shared__ __align__(16) bf16 As[128 * 264];
    const int b = blockIdx.x;
    const bool sel = b >= 256;
    const int m0 = (b & 255) * 128;
    const float* A  = sel ? kvin : qin;
    const bf16*  Bw = sel ? Wkv : Wqg;
    bf16*        Cc = sel ? KV : QG;

    const int tid = threadIdx.x, lane = tid & 63, wave = tid >> 6;
    const int quad = lane >> 4, lc = lane & 15;
    const int wr = wave & 1, wc = wave >> 1;

    // ---- stage whole 128x256 A tile (fp32 -> bf16), one barrier ----
    {
        const int r = tid >> 2, qtr = tid & 3;           // row, 64-col quarter
        const float* src = A + (size_t)(m0 + r) * 256 + qtr * 64;
        bf16* dst = As + r * 264 + qtr * 64;
        #pragma unroll
        for (int g = 0; g < 4; ++g) {
            float4 x0 = *(const float4*)(src + g * 16);
            float4 x1 = *(const float4*)(src + g * 16 + 4);
            float4 x2 = *(const float4*)(src + g * 16 + 8);
            float4 x3 = *(const float4*)(src + g * 16 + 12);
            bf16x8 t0, t1;
            t0[0]=(bf16)x0.x; t0[1]=(bf16)x0.y; t0[2]=(bf16)x0.z; t0[3]=(bf16)x0.w;
            t0[4]=(bf16)x1.x; t0[5]=(bf16)x1.y; t0[6]=(bf16)x1.z; t0[7]=(bf16)x1.w;
            t1[0]=(bf16)x2.x; t1[1]=(bf16)x2.y; t1[2]=(bf16)x2.z; t1[3]=(bf16)x2.w;
            t1[4]=(bf16)x3.x; t1[5]=(bf16)x3.y; t1[6]=(bf16)x3.z; t1[7]=(bf16)x3.w;
            *(bf16x8*)(dst + g * 16)     = t0;
            *(bf16x8*)(dst + g * 16 + 8) = t1;
        }
    }
    __syncthreads();

    f32x4 acc[4][8];
    #pragma unroll
    for (int i = 0; i < 4; ++i)
        #pragma unroll
        for (int j = 0; j < 8; ++j) acc[i][j] = f32x4{0.f, 0.f, 0.f, 0.f};

    #pragma unroll 2
    for (int kb = 0; kb < 8; ++kb) {
        const int ko = kb * 32;
        bf16x8 aF[4], bF[8];
        #pragma unroll
        for (int mt = 0; mt < 4; ++mt)
            aF[mt] = *(const bf16x8*)(As + (wr * 64 + mt * 16 + lc) * 264 + ko + quad * 8);
        #pragma unroll
        for (int nt = 0; nt < 8; ++nt)
            bF[nt] = *(const bf16x8*)(Bw + (size_t)(wc * 128 + nt * 16 + lc) * 256 + ko + quad * 8);
        #pragma unroll
        for (int mt = 0; mt < 4; ++mt)
            #pragma unroll
            for (int nt = 0; nt < 8; ++nt)
                acc[mt][nt] = MFMA16(aF[mt], bF[nt], acc[mt][nt]);
    }

    #pragma unroll
    for (int mt = 0; mt < 4; ++mt)
        #pragma unroll
        for (int nt = 0; nt < 8; ++nt) {
            const int row = m0 + wr * 64 + mt * 16 + quad * 4;
            const int col = wc * 128 + nt * 16 + lc;
            #pragma unroll
            for (int rr = 0; rr < 4; ++rr)
                Cc[(size_t)(row + rr) * 512 + col] = (bf16)acc[mt][nt][rr];
        }
}

// ================= attention per (s,h): 256 thr, transposed-score scheme =======
// LDS: mask[256]f32 @0 | Ks[256][36] @1024 | Vt[32][260] @19456  = 36096 B -> 4 blk/CU
#define A_LDS_TOT (1024 + 18432 + 16640)

__global__ __launch_bounds__(256, 4) void attn_kernel(
    const bf16* __restrict__ QG, const bf16* __restrict__ KV,
    const float* __restrict__ biasC, const float* __restrict__ bias_mask,
    const float* __restrict__ b_g, bf16* __restrict__ OGh)
{
    __shared__ __align__(16) char smem[A_LDS_TOT];
    float* maskadd = (float*)(smem);
    bf16*  Ks      = (bf16*)(smem + 1024);
    bf16*  Vt      = (bf16*)(smem + 19456);

    const int tid  = threadIdx.x;
    const int wave = tid >> 6, lane = tid & 63;
    const int quad = lane >> 4, lc = lane & 15;
    const int h = blockIdx.x & 7;        // h <-> XCD: biasC[h] (256 KB) stays L2-hot
    const int s = blockIdx.x >> 3;

    maskadd[tid] = (bias_mask[s * 256 + tid] - 1.0f) * 1e9f;
    {   // stage K rows and V^T (no permutation needed in this scheme)
        const bf16* kvrow = KV + (size_t)(s * 256 + tid) * 512 + h * 32;
        #pragma unroll
        for (int j = 0; j < 4; ++j)
            *(bf16x8*)(Ks + tid * 36 + j * 8) = *(const bf16x8*)(kvrow + j * 8);
        bf16x8 vx[4];
        #pragma unroll
        for (int j = 0; j < 4; ++j) vx[j] = *(const bf16x8*)(kvrow + 256 + j * 8);
        #pragma unroll
        for (int d = 0; d < 32; ++d)
            Vt[d * 260 + tid] = vx[d >> 3][d & 7];
    }
    __syncthreads();   // only barrier

    const bf16* qbase = QG + (size_t)(s * 256) * 512 + h * 32;
    const bf16* gbase = qbase + 256;

    #pragma unroll 1
    for (int p = 0; p < 4; ++p) {
        const int qt = wave * 4 + p;
        const int q0 = qt * 16;
        // Q fragment (B-operand: n = q, k = d)
        bf16x8 qf = *(const bf16x8*)(qbase + (size_t)(q0 + lc) * 512 + quad * 8);
        const float* bC = biasC + (size_t)(h * 16 + qt) * 4096 + quad * 64 + lc * 4;

        f32x4 o0 = {0.f,0.f,0.f,0.f}, o1 = {0.f,0.f,0.f,0.f};
        float persum = 0.f;

        #pragma unroll
        for (int kt = 0; kt < 16; ++kt) {
            // K fragment (A-operand: m = k-row, k = d)
            bf16x8 kf = *(const bf16x8*)(Ks + (kt * 16 + lc) * 36 + quad * 8);
            // C-init: bias (per-lane float4 over rr=k) + mask (LDS broadcast float4)
            f32x4 ci = *(const f32x4*)(bC + kt * 256);
            float4 mv = *(const float4*)(maskadd + kt * 16 + quad * 4);
            ci[0] += mv.x; ci[1] += mv.y; ci[2] += mv.z; ci[3] += mv.w;
            // S^T tile: rows = k (quad*4+rr), cols = q (lc)
            f32x4 st = MFMA16(kf, qf, ci);
            // exp (unnormalized P) — C-layout of S^T == A-layout of 16x16x16 MFMA
            bf16x4 pk;
            #pragma unroll
            for (int rr = 0; rr < 4; ++rr) {
                float e = __expf(st[rr]);
                persum += e;
                pk[rr] = (bf16)e;
            }
            short4_ pks = __builtin_bit_cast(short4_, pk);
            short4_ v0 = __builtin_bit_cast(short4_, *(const bf16x4*)(Vt + lc * 260 + kt * 16 + quad * 4));
            short4_ v1 = __builtin_bit_cast(short4_, *(const bf16x4*)(Vt + (16 + lc) * 260 + kt * 16 + quad * 4));
            o0 = MFMA161(pks, v0, o0);
            o1 = MFMA161(pks, v1, o1);
        }

        // softmax denominator: sum over k = sum over quads (this lane holds q = lc)
        persum += __shfl_xor(persum, 16, 64);
        persum += __shfl_xor(persum, 32, 64);
        const float inv = 1.0f / persum;
        // O rows are q = quad*4+rr -> fetch inv for those q's (lane lc = q, hi = 0)
        float invr[4];
        #pragma unroll
        for (int rr = 0; rr < 4; ++rr) invr[rr] = __shfl(inv, quad * 4 + rr, 64);

        // gate + scale + store (full-line writes in OGh[h][m][32])
        const size_t obase = ((size_t)h * 32768 + s * 256 + q0 + quad * 4) * 32;
        #pragma unroll
        for (int nt = 0; nt < 2; ++nt) {
            f32x4 ov = nt ? o1 : o0;
            float bg = b_g[h * 32 + nt * 16 + lc];
            #pragma unroll
            for (int rr = 0; rr < 4; ++rr) {
                float gp = (float)gbase[(size_t)(q0 + quad * 4 + rr) * 512 + nt * 16 + lc] + bg;
                float g = 1.0f / (1.0f + __expf(-gp));
                OGh[obase + (size_t)rr * 32 + nt * 16 + lc] = (bf16)(ov[rr] * invr[rr] * g);
            }
        }
    }
}

// ========= outproj: out = OGh @ Wo^T + b_o.  256 thr, full-K staging ==========
__global__ __launch_bounds__(256, 2) void outproj_kernel(
    const bf16* __restrict__ OGh, const bf16* __restrict__ Wo,
    const float* __restrict__ bo, float* __restrict__ out)
{
    __shared__ __align__(16) bf16 As[128 * 264];
    const int m0 = blockIdx.x * 128;
    const int tid = threadIdx.x, lane = tid & 63, wave = tid >> 6;
    const int quad = lane >> 4, lc = lane & 15;
    const int wr = wave & 1, wc = wave >> 1;

    {   // gather A rows from [h][m][32] into [m][hd]
        const int r = tid >> 1, half = tid & 1;
        #pragma unroll
        for (int kb = 0; kb < 8; ++kb) {
            const bf16* src = OGh + ((size_t)kb * 32768 + m0 + r) * 32 + half * 16;
            bf16x8 t0 = *(const bf16x8*)(src);
            bf16x8 t1 = *(const bf16x8*)(src + 8);
            *(bf16x8*)(As + r * 264 + kb * 32 + half * 16)     = t0;
            *(bf16x8*)(As + r * 264 + kb * 32 + half * 16 + 8) = t1;
        }
    }
    __syncthreads();

    f32x4 acc[4][8];
    #pragma unroll
    for (int i = 0; i < 4; ++i)
        #pragma unroll
        for (int j = 0; j < 8; ++j) acc[i][j] = f32x4{0.f, 0.f, 0.f, 0.f};

    #pragma unroll 2
    for (int kb = 0; kb < 8; ++kb) {
        const int ko = kb * 32;
        bf16x8 aF[4], bF[8];
        #pragma unroll
        for (int mt = 0; mt < 4; ++mt)
            aF[mt] = *(const bf16x8*)(As + (wr * 64 + mt * 16 + lc) * 264 + ko + quad * 8);
        #pragma unroll
        for (int nt = 0; nt < 8; ++nt)
            bF[nt] = *(const bf16x8*)(Wo + (size_t)(wc * 128 + nt * 16 + lc) * 256 + ko + quad * 8);
        #pragma unroll
        for (int mt = 0; mt < 4; ++mt)
            #pragma unroll
            for (int nt = 0; nt < 8; ++nt)
                acc[mt][nt] = MFMA16(aF[mt], bF[nt], acc[mt][nt]);
    }

    #pragma unroll
    for (int mt = 0; mt < 4; ++mt)
        #pragma unroll
        for (int nt = 0; nt < 8; ++nt) {
            const int row = m0 + wr * 64 + mt * 16 + quad * 4;
            const int col = wc * 128 + nt * 16 + lc;
            const float b = bo[col];
            #pragma unroll
            for (int rr = 0; rr < 4; ++rr)
                out[(size_t)(row + rr) * 256 + col] = acc[mt][nt][rr] + b;
        }
}

// ================= launch =================
extern "C" void kernel_launch(void* const* d_in, const int* in_sizes, int n_in,
                              void* d_out, int out_size, void* d_ws, size_t ws_size,
                              hipStream_t stream)
{
    (void)in_sizes; (void)n_in; (void)out_size; (void)ws_size;
    const float* q    = (const float*)d_in[0];
    const float* kv   = (const float*)d_in[1];
    const float* bias = (const float*)d_in[2];
    const float* mask = (const float*)d_in[3];
    const float* w_q  = (const float*)d_in[4];
    const float* w_k  = (const float*)d_in[5];
    const float* w_v  = (const float*)d_in[6];
    const float* w_g  = (const float*)d_in[7];
    const float* b_g  = (const float*)d_in[8];
    const float* w_o  = (const float*)d_in[9];
    const float* b_o  = (const float*)d_in[10];
    float* out = (float*)d_out;

    char* ws = (char*)d_ws;
    bf16*  QG    = (bf16*)(ws + 0);           // 33.55 MB  [32768][512] = [Q*norm | G]
    bf16*  KV    = (bf16*)(ws + 33554432);    // 33.55 MB  [32768][512] = [K | V]
    bf16*  OGh   = (bf16*)(ws + 67108864);    // 16.78 MB  [8][32768][32]
    float* biasC = (float*)(ws + 83886080);   //  2.10 MB  [h][tq][kt][quad][lc][rr]
    bf16*  Wqg   = (bf16*)(ws + 85983232);    //  0.26 MB
    bf16*  Wkv   = (bf16*)(ws + 86245376);    //  0.26 MB
    bf16*  Wo    = (bf16*)(ws + 86507520);    //  0.13 MB

    prep_kernel<<<416, 256, 0, stream>>>(bias, w_q, w_k, w_v, w_g, w_o,
                                         biasC, Wqg, Wkv, Wo);
    proj_kernel<<<512, 512, 0, stream>>>(q, kv, Wqg, Wkv, QG, KV);
    attn_kernel<<<1024, 256, 0, stream>>>(QG, KV, biasC, mask, b_g, OGh);
    outproj_kernel<<<256, 256, 0, stream>>>(OGh, Wo, b_o, out);
}

// Round 6
// 320.416 us; speedup vs baseline: 1.0293x; 1.0293x over previous
//
#include <hip/hip_runtime.h>

typedef __bf16 bf16;
typedef __bf16 bf16x8 __attribute__((ext_vector_type(8)));
typedef __bf16 bf16x4 __attribute__((ext_vector_type(4)));
typedef short  short4_ __attribute__((ext_vector_type(4)));
typedef float  f32x4  __attribute__((ext_vector_type(4)));

#define MFMA16(a, b, c)  __builtin_amdgcn_mfma_f32_16x16x32_bf16((a), (b), (c), 0, 0, 0)
#define MFMA161(a, b, c) __builtin_amdgcn_mfma_f32_16x16x16bf16_1k((a), (b), (c), 0, 0, 0)

// B=1, S=128, R=256, C=256, H=8, Ca=32.  M = S*R = 32768.
// Per-head layouts: Qh/Gh/Kh/Vh/OGh [h][32768][32] bf16 — dense, block-private lines.

// ================= prep: weights transpose + bias repack =================
// biasC[h][tq][kt][quad][lc][rr]  <->  bias[q = tq*16+lc][k = kt*16+quad*4+rr][h]
__global__ __launch_bounds__(256) void prep_kernel(
    const float* __restrict__ bias,
    const float* __restrict__ w_q, const float* __restrict__ w_k,
    const float* __restrict__ w_v, const float* __restrict__ w_g,
    const float* __restrict__ w_o,
    float* __restrict__ biasC,
    bf16* __restrict__ Wqg, bf16* __restrict__ Wkv, bf16* __restrict__ Wo)
{
    const float norm = 0.17677669529663687f;  // 1/sqrt(32) baked into Wq
    const int gid = blockIdx.x * 256 + threadIdx.x;
    const int gsz = gridDim.x * 256;
    for (int u = gid; u < 851968; u += gsz) {
        if (u < 131072) {                 // Wqg[n][k]
            int n = u >> 8, k = u & 255;
            float v = (n < 256) ? w_q[k * 256 + n] * norm : w_g[k * 256 + (n - 256)];
            Wqg[u] = (bf16)v;
        } else if (u < 262144) {          // Wkv[n][k]
            int i = u - 131072;
            int n = i >> 8, k = i & 255;
            float v = (n < 256) ? w_k[k * 256 + n] : w_v[k * 256 + (n - 256)];
            Wkv[i] = (bf16)v;
        } else if (u < 327680) {          // Wo[c][hd]
            int i = u - 262144;
            int n = i >> 8, k = i & 255;
            Wo[i] = (bf16)w_o[k * 256 + n];
        } else {                          // biasC (transposed pack for S^T scores)
            int o = u - 327680;
            int rr = o & 3, lc = (o >> 2) & 15, quad = (o >> 6) & 3;
            int kt = (o >> 8) & 15, tq = (o >> 12) & 15, h = o >> 16;
            int q = tq * 16 + lc, k = kt * 16 + quad * 4 + rr;
            biasC[o] = bias[((q << 8) + k) * 8 + h];
        }
    }
}

// ========== proj: per-head Q/G (from q) and K/V (from kv) =====================
// 512 thr; block tile 128m x 512n (full N); wave 64m x 128n. Full-K LDS A-staging.
// Epilogue: C tile bounced through As-LDS, stored as 16B/lane full-line chunks.
__global__ __launch_bounds__(512, 2) void proj_kernel(
    const float* __restrict__ qin, const float* __restrict__ kvin,
    const bf16* __restrict__ Wqg, const bf16* __restrict__ Wkv,
    bf16* __restrict__ Qh, bf16* __restrict__ Gh,
    bf16* __restrict__ Kh, bf16* __restrict__ Vh)
{
    __shared__ __align__(16) bf16 As[128 * 264];   // also reused as C-bounce
    const int b = blockIdx.x;
    const bool sel = b >= 256;
    const int m0 = (b & 255) * 128;
    const float* A  = sel ? kvin : qin;
    const bf16*  Bw = sel ? Wkv : Wqg;
    bf16* dst0 = sel ? Kh : Qh;    // n < 256
    bf16* dst1 = sel ? Vh : Gh;    // n >= 256

    const int tid = threadIdx.x, lane = tid & 63, wave = tid >> 6;
    const int quad = lane >> 4, lc = lane & 15;
    const int wr = wave & 1, wc = wave >> 1;

    {   // stage whole 128x256 A tile (fp32 -> bf16)
        const int r = tid >> 2, qtr = tid & 3;
        const float* src = A + (size_t)(m0 + r) * 256 + qtr * 64;
        bf16* dst = As + r * 264 + qtr * 64;
        #pragma unroll
        for (int g = 0; g < 4; ++g) {
            float4 x0 = *(const float4*)(src + g * 16);
            float4 x1 = *(const float4*)(src + g * 16 + 4);
            float4 x2 = *(const float4*)(src + g * 16 + 8);
            float4 x3 = *(const float4*)(src + g * 16 + 12);
            bf16x8 t0, t1;
            t0[0]=(bf16)x0.x; t0[1]=(bf16)x0.y; t0[2]=(bf16)x0.z; t0[3]=(bf16)x0.w;
            t0[4]=(bf16)x1.x; t0[5]=(bf16)x1.y; t0[6]=(bf16)x1.z; t0[7]=(bf16)x1.w;
            t1[0]=(bf16)x2.x; t1[1]=(bf16)x2.y; t1[2]=(bf16)x2.z; t1[3]=(bf16)x2.w;
            t1[4]=(bf16)x3.x; t1[5]=(bf16)x3.y; t1[6]=(bf16)x3.z; t1[7]=(bf16)x3.w;
            *(bf16x8*)(dst + g * 16)     = t0;
            *(bf16x8*)(dst + g * 16 + 8) = t1;
        }
    }
    __syncthreads();

    f32x4 acc[4][8];
    #pragma unroll
    for (int i = 0; i < 4; ++i)
        #pragma unroll
        for (int j = 0; j < 8; ++j) acc[i][j] = f32x4{0.f, 0.f, 0.f, 0.f};

    #pragma unroll 2
    for (int kb = 0; kb < 8; ++kb) {
        const int ko = kb * 32;
        bf16x8 aF[4], bF[8];
        #pragma unroll
        for (int mt = 0; mt < 4; ++mt)
            aF[mt] = *(const bf16x8*)(As + (wr * 64 + mt * 16 + lc) * 264 + ko + quad * 8);
        #pragma unroll
        for (int nt = 0; nt < 8; ++nt)
            bF[nt] = *(const bf16x8*)(Bw + (size_t)(wc * 128 + nt * 16 + lc) * 256 + ko + quad * 8);
        #pragma unroll
        for (int mt = 0; mt < 4; ++mt)
            #pragma unroll
            for (int nt = 0; nt < 8; ++nt)
                acc[mt][nt] = MFMA16(aF[mt], bF[nt], acc[mt][nt]);
    }
    __syncthreads();   // As reads done; reuse as C bounce

    #pragma unroll 1
    for (int ph = 0; ph < 2; ++ph) {
        if ((wc >> 1) == ph) {
            const int cl0 = (wc & 1) * 128;
            #pragma unroll
            for (int mt = 0; mt < 4; ++mt)
                #pragma unroll
                for (int nt = 0; nt < 8; ++nt) {
                    const int r = wr * 64 + mt * 16 + quad * 4;
                    #pragma unroll
                    for (int rr = 0; rr < 4; ++rr)
                        As[(r + rr) * 264 + cl0 + nt * 16 + lc] = (bf16)acc[mt][nt][rr];
                }
        }
        __syncthreads();
        bf16* dst = ph ? dst1 : dst0;
        #pragma unroll
        for (int j = 0; j < 8; ++j) {
            const int idx = j * 512 + tid;           // 4096 16B-chunks
            const int r = idx >> 5, c8 = idx & 31;
            bf16x8 v = *(const bf16x8*)(As + r * 264 + c8 * 8);
            const int hh = c8 >> 2, d0 = (c8 & 3) * 8;
            *(bf16x8*)(dst + ((size_t)hh * 32768 + m0 + r) * 32 + d0) = v;
        }
        __syncthreads();
    }
}

// ================= attention per (s,h): 256 thr, transposed-score scheme =======
// LDS: mask[256]f32 @0 | Ks[256][34] @1024 | Vt[32][258] @18432 | Ot 4x[16][36] @34944
#define A_LDS_TOT (1024 + 17408 + 16512 + 4608)   // 39552 B -> 4 blocks/CU

__global__ __launch_bounds__(256, 4) void attn_kernel(
    const bf16* __restrict__ Qh, const bf16* __restrict__ Gh,
    const bf16* __restrict__ Kh, const bf16* __restrict__ Vh,
    const float* __restrict__ biasC, const float* __restrict__ bias_mask,
    const float* __restrict__ b_g, bf16* __restrict__ OGh)
{
    __shared__ __align__(16) char smem[A_LDS_TOT];
    float* maskadd = (float*)(smem);
    bf16*  Ks      = (bf16*)(smem + 1024);
    bf16*  Vt      = (bf16*)(smem + 18432);

    const int tid  = threadIdx.x;
    const int wave = tid >> 6, lane = tid & 63;
    const int quad = lane >> 4, lc = lane & 15;
    const int h = blockIdx.x & 7;        // h <-> XCD: biasC[h] (256 KB) stays L2-hot
    const int s = blockIdx.x >> 3;
    const size_t hbase = (size_t)h * 32768 + s * 256;

    maskadd[tid] = (bias_mask[s * 256 + tid] - 1.0f) * 1e9f;
    {   // stage K rows (dense 64B/row) and V^T
        const bf16* kr = Kh + (hbase + tid) * 32;
        #pragma unroll
        for (int j = 0; j < 4; ++j)
            *(bf16x8*)(Ks + tid * 34 + j * 8) = *(const bf16x8*)(kr + j * 8);
        const bf16* vr = Vh + (hbase + tid) * 32;
        bf16x8 vx[4];
        #pragma unroll
        for (int j = 0; j < 4; ++j) vx[j] = *(const bf16x8*)(vr + j * 8);
        #pragma unroll
        for (int d = 0; d < 32; ++d)
            Vt[d * 258 + tid] = vx[d >> 3][d & 7];
    }
    __syncthreads();   // only barrier

    bf16* Ot = (bf16*)(smem + 34944) + wave * (16 * 36);
    const int orow = lane >> 2, ocol = (lane & 3) * 8;
    float bgv[8];
    #pragma unroll
    for (int j = 0; j < 8; ++j) bgv[j] = b_g[h * 32 + ocol + j];

    #pragma unroll 1
    for (int p = 0; p < 4; ++p) {
        const int qt = wave * 4 + p;
        const int q0 = qt * 16;
        // Q fragment (B-operand: n = q, k = d) — dense 1KB/wave read
        bf16x8 qf = *(const bf16x8*)(Qh + (hbase + q0 + lc) * 32 + quad * 8);
        const float* bC = biasC + (size_t)(h * 16 + qt) * 4096 + quad * 64 + lc * 4;

        f32x4 o0 = {0.f,0.f,0.f,0.f}, o1 = {0.f,0.f,0.f,0.f};
        float persum = 0.f;

        #pragma unroll
        for (int kt = 0; kt < 16; ++kt) {
            bf16x8 kf = *(const bf16x8*)(Ks + (kt * 16 + lc) * 34 + quad * 8);
            f32x4 ci = *(const f32x4*)(bC + kt * 256);
            float4 mv = *(const float4*)(maskadd + kt * 16 + quad * 4);
            ci[0] += mv.x; ci[1] += mv.y; ci[2] += mv.z; ci[3] += mv.w;
            f32x4 st = MFMA16(kf, qf, ci);   // S^T: rows=k, cols=q
            bf16x4 pk;
            #pragma unroll
            for (int rr = 0; rr < 4; ++rr) {
                float e = __expf(st[rr]);
                persum += e;
                pk[rr] = (bf16)e;
            }
            short4_ pks = __builtin_bit_cast(short4_, pk);
            short4_ v0 = __builtin_bit_cast(short4_, *(const bf16x4*)(Vt + lc * 258 + kt * 16 + quad * 4));
            short4_ v1 = __builtin_bit_cast(short4_, *(const bf16x4*)(Vt + (16 + lc) * 258 + kt * 16 + quad * 4));
            o0 = MFMA161(pks, v0, o0);
            o1 = MFMA161(pks, v1, o1);
        }

        persum += __shfl_xor(persum, 16, 64);
        persum += __shfl_xor(persum, 32, 64);
        const float inv = 1.0f / persum;
        float invr[4];
        #pragma unroll
        for (int rr = 0; rr < 4; ++rr) invr[rr] = __shfl(inv, quad * 4 + rr, 64);

        // O (C-layout) -> per-wave LDS tile (wave-private, no barrier)
        #pragma unroll
        for (int nt = 0; nt < 2; ++nt) {
            f32x4 ov = nt ? o1 : o0;
            #pragma unroll
            for (int rr = 0; rr < 4; ++rr)
                Ot[(quad * 4 + rr) * 36 + nt * 16 + lc] = (bf16)(ov[rr] * invr[rr]);
        }
        // read back row-major, gate, store full-line (1KB/wave-instruction)
        bf16x8 o8 = *(const bf16x8*)(Ot + orow * 36 + ocol);
        bf16x8 g8 = *(const bf16x8*)(Gh + (hbase + q0 + orow) * 32 + ocol);
        bf16x8 res;
        #pragma unroll
        for (int j = 0; j < 8; ++j) {
            float gp = (float)g8[j] + bgv[j];
            float gg = 1.0f / (1.0f + __expf(-gp));
            res[j] = (bf16)((float)o8[j] * gg);
        }
        *(bf16x8*)(OGh + (hbase + q0 + orow) * 32 + ocol) = res;
    }
}

// ========= outproj: out = OGh-gather @ Wo^T + b_o.  256 thr, full-K ==========
__global__ __launch_bounds__(256, 2) void outproj_kernel(
    const bf16* __restrict__ OGh, const bf16* __restrict__ Wo,
    const float* __restrict__ bo, float* __restrict__ out)
{
    __shared__ __align__(16) char smem_c[128 * 264 * 2];   // As (bf16) / Csf (fp32)
    bf16*  As  = (bf16*)smem_c;
    float* Csf = (float*)smem_c;                            // [128][132]
    const int m0 = blockIdx.x * 128;
    const int tid = threadIdx.x, lane = tid & 63, wave = tid >> 6;
    const int quad = lane >> 4, lc = lane & 15;
    const int wr = wave & 1, wc = wave >> 1;

    {   // gather A rows from [h][m][32] into [m][hd] — dense 64B pieces
        const int r = tid >> 1, half = tid & 1;
        #pragma unroll
        for (int kb = 0; kb < 8; ++kb) {
            const bf16* src = OGh + ((size_t)kb * 32768 + m0 + r) * 32 + half * 16;
            bf16x8 t0 = *(const bf16x8*)(src);
            bf16x8 t1 = *(const bf16x8*)(src + 8);
            *(bf16x8*)(As + r * 264 + kb * 32 + half * 16)     = t0;
            *(bf16x8*)(As + r * 264 + kb * 32 + half * 16 + 8) = t1;
        }
    }
    __syncthreads();

    f32x4 acc[4][8];
    #pragma unroll
    for (int i = 0; i < 4; ++i)
        #pragma unroll
        for (int j = 0; j < 8; ++j) acc[i][j] = f32x4{0.f, 0.f, 0.f, 0.f};

    #pragma unroll 2
    for (int kb = 0; kb < 8; ++kb) {
        const int ko = kb * 32;
        bf16x8 aF[4], bF[8];
        #pragma unroll
        for (int mt = 0; mt < 4; ++mt)
            aF[mt] = *(const bf16x8*)(As + (wr * 64 + mt * 16 + lc) * 264 + ko + quad * 8);
        #pragma unroll
        for (int nt = 0; nt < 8; ++nt)
            bF[nt] = *(const bf16x8*)(Wo + (size_t)(wc * 128 + nt * 16 + lc) * 256 + ko + quad * 8);
        #pragma unroll
        for (int mt = 0; mt < 4; ++mt)
            #pragma unroll
            for (int nt = 0; nt < 8; ++nt)
                acc[mt][nt] = MFMA16(aF[mt], bF[nt], acc[mt][nt]);
    }
    __syncthreads();   // As reads done; reuse as fp32 C bounce

    #pragma unroll 1
    for (int ph = 0; ph < 2; ++ph) {
        if (wc == ph) {
            #pragma unroll
            for (int mt = 0; mt < 4; ++mt)
                #pragma unroll
                for (int nt = 0; nt < 8; ++nt) {
                    const int r = wr * 64 + mt * 16 + quad * 4;
                    const int cl = nt * 16 + lc;
                    const float bb = bo[ph * 128 + cl];
                    #pragma unroll
                    for (int rr = 0; rr < 4; ++rr)
                        Csf[(r + rr) * 132 + cl] = acc[mt][nt][rr] + bb;
                }
        }
        __syncthreads();
        #pragma unroll
        for (int j = 0; j < 16; ++j) {
            const int idx = j * 256 + tid;           // 4096 float4 chunks
            const int r = idx >> 5, c4 = idx & 31;
            float4 v = *(const float4*)(Csf + r * 132 + c4 * 4);
            *(float4*)(out + (size_t)(m0 + r) * 256 + ph * 128 + c4 * 4) = v;
        }
        __syncthreads();
    }
}

// ================= launch =================
extern "C" void kernel_launch(void* const* d_in, const int* in_sizes, int n_in,
                              void* d_out, int out_size, void* d_ws, size_t ws_size,
                              hipStream_t stream)
{
    (void)in_sizes; (void)n_in; (void)out_size; (void)ws_size;
    const float* q    = (const float*)d_in[0];
    const float* kv   = (const float*)d_in[1];
    const float* bias = (const float*)d_in[2];
    const float* mask = (const float*)d_in[3];
    const float* w_q  = (const float*)d_in[4];
    const float* w_k  = (const float*)d_in[5];
    const float* w_v  = (const float*)d_in[6];
    const float* w_g  = (const float*)d_in[7];
    const float* b_g  = (const float*)d_in[8];
    const float* w_o  = (const float*)d_in[9];
    const float* b_o  = (const float*)d_in[10];
    float* out = (float*)d_out;

    char* ws = (char*)d_ws;
    bf16*  Qh    = (bf16*)(ws + 0);           // 16.78 MB [8][32768][32]
    bf16*  Gh    = (bf16*)(ws + 16777216);    // 16.78 MB
    bf16*  Kh    = (bf16*)(ws + 33554432);    // 16.78 MB
    bf16*  Vh    = (bf16*)(ws + 50331648);    // 16.78 MB
    bf16*  OGh   = (bf16*)(ws + 67108864);    // 16.78 MB
    float* biasC = (float*)(ws + 83886080);   //  2.10 MB [h][tq][kt][quad][lc][rr]
    bf16*  Wqg   = (bf16*)(ws + 85983232);    //  0.26 MB
    bf16*  Wkv   = (bf16*)(ws + 86245376);    //  0.26 MB
    bf16*  Wo    = (bf16*)(ws + 86507520);    //  0.13 MB

    prep_kernel<<<416, 256, 0, stream>>>(bias, w_q, w_k, w_v, w_g, w_o,
                                         biasC, Wqg, Wkv, Wo);
    proj_kernel<<<512, 512, 0, stream>>>(q, kv, Wqg, Wkv, Qh, Gh, Kh, Vh);
    attn_kernel<<<1024, 256, 0, stream>>>(Qh, Gh, Kh, Vh, biasC, mask, b_g, OGh);
    outproj_kernel<<<256, 256, 0, stream>>>(OGh, Wo, b_o, out);
}